// Round 1
// baseline (88.168 us; speedup 1.0000x reference)
//
#include <hip/hip_runtime.h>
#include <math.h>

#define DSZ   64
#define NVOX  (DSZ*DSZ*DSZ)
#define NSTEP 7

// ---------- SE(3) exp: xi=(v,w) -> R(3x3 row-major), t(3) ----------
__device__ __forceinline__ void se3_exp_dev(const float xi[6], float R[9], float t[3]) {
    float vx = xi[0], vy = xi[1], vz = xi[2];
    float wx = xi[3], wy = xi[4], wz = xi[5];
    float t2 = wx*wx + wy*wy + wz*wz;
    float theta = sqrtf(t2);
    float A, B, C;
    if (theta < 1e-4f) {
        A = 1.0f - t2*(1.0f/6.0f);
        B = 0.5f - t2*(1.0f/24.0f);
        C = (1.0f/6.0f) - t2*(1.0f/120.0f);
    } else {
        float s, c;
        sincosf(theta, &s, &c);
        A = s/theta;
        B = (1.0f - c)/t2;
        C = (theta - s)/(t2*theta);
    }
    float xx = wx*wx, yy = wy*wy, zz = wz*wz;
    float xy = wx*wy, xz = wx*wz, yz = wy*wz;
    // R = I + A*Wm + B*W2
    R[0] = 1.0f - B*(yy+zz);
    R[1] = -A*wz + B*xy;
    R[2] =  A*wy + B*xz;
    R[3] =  A*wz + B*xy;
    R[4] = 1.0f - B*(xx+zz);
    R[5] = -A*wx + B*yz;
    R[6] = -A*wy + B*xz;
    R[7] =  A*wx + B*yz;
    R[8] = 1.0f - B*(xx+yy);
    // V = I + B*Wm + C*W2 ; t = V @ v
    float V0 = 1.0f - C*(yy+zz);
    float V1 = -B*wz + C*xy;
    float V2 =  B*wy + C*xz;
    float V3 =  B*wz + C*xy;
    float V4 = 1.0f - C*(xx+zz);
    float V5 = -B*wx + C*yz;
    float V6 = -B*wy + C*xz;
    float V7 =  B*wx + C*yz;
    float V8 = 1.0f - C*(xx+yy);
    t[0] = V0*vx + V1*vy + V2*vz;
    t[1] = V3*vx + V4*vy + V5*vz;
    t[2] = V6*vx + V7*vy + V8*vz;
}

// ---------- SE(3) log: R,t -> xi=(v,w) ----------
__device__ __forceinline__ void se3_log_dev(const float R[9], const float t[3], float out[6]) {
    float tr = R[0] + R[4] + R[8];
    float cs = (tr - 1.0f)*0.5f;
    cs = fminf(fmaxf(cs, -1.0f + 1e-6f), 1.0f - 1e-6f);
    float theta = acosf(cs);
    float t2 = theta*theta;
    float fac, coef;
    if (theta < 1e-4f) {
        fac  = 1.0f + t2*(1.0f/6.0f);
        coef = 1.0f/12.0f;
    } else {
        float s, c;
        sincosf(theta, &s, &c);
        fac = theta/s;
        float A = s/theta;
        float B = (1.0f - c)/t2;
        coef = (1.0f - A/(2.0f*B))/t2;
    }
    float wx = 0.5f*(R[7]-R[5])*fac;   // S[2][1]
    float wy = 0.5f*(R[2]-R[6])*fac;   // S[0][2]
    float wz = 0.5f*(R[3]-R[1])*fac;   // S[1][0]
    float xx = wx*wx, yy = wy*wy, zz = wz*wz;
    float xy = wx*wy, xz = wx*wz, yz = wy*wz;
    // Vinv = I - 0.5*Wm + coef*W2 ; v = Vinv @ t
    float V0 = 1.0f - coef*(yy+zz);
    float V1 =  0.5f*wz + coef*xy;
    float V2 = -0.5f*wy + coef*xz;
    float V3 = -0.5f*wz + coef*xy;
    float V4 = 1.0f - coef*(xx+zz);
    float V5 =  0.5f*wx + coef*yz;
    float V6 =  0.5f*wy + coef*xz;
    float V7 = -0.5f*wx + coef*yz;
    float V8 = 1.0f - coef*(xx+yy);
    out[0] = V0*t[0] + V1*t[1] + V2*t[2];
    out[1] = V3*t[0] + V4*t[1] + V5*t[2];
    out[2] = V6*t[0] + V7*t[1] + V8*t[2];
    out[3] = wx; out[4] = wy; out[5] = wz;
}

// ---------- init: transpose (6,N)->(N,6) * scale, and mulMat = exp ----------
__global__ __launch_bounds__(256) void init_kernel(const float* __restrict__ in,
                                                   float* __restrict__ vec,
                                                   float* __restrict__ mul) {
    int n = blockIdx.x*256 + threadIdx.x;
    const float scale = 1.0f/128.0f;  // 1/2^NSTEP
    float xi[6];
#pragma unroll
    for (int c = 0; c < 6; ++c) xi[c] = in[c*NVOX + n]*scale;
    float R[9], t[3];
    se3_exp_dev(xi, R, t);
    float4* mp = reinterpret_cast<float4*>(mul + (size_t)n*12);
    mp[0] = make_float4(R[0], R[1], R[2], t[0]);
    mp[1] = make_float4(R[3], R[4], R[5], t[1]);
    mp[2] = make_float4(R[6], R[7], R[8], t[2]);
    float2* vp = reinterpret_cast<float2*>(vec + (size_t)n*6);
    vp[0] = make_float2(xi[0], xi[1]);
    vp[1] = make_float2(xi[2], xi[3]);
    vp[2] = make_float2(xi[4], xi[5]);
}

// ---------- one squaring step ----------
__global__ __launch_bounds__(256) void step_kernel(const float* __restrict__ vin,
                                                   float* __restrict__ vout,
                                                   float* __restrict__ mul) {
    int n = blockIdx.x*256 + threadIdx.x;
    // load current mulMat (rows of [R|t])
    float4* mp = reinterpret_cast<float4*>(mul + (size_t)n*12);
    float4 r0 = mp[0], r1 = mp[1], r2 = mp[2];

    // fixed grid point for this voxel: n = i*4096 + j*64 + k, ax = (2*idx-63)/63
    int k = n & 63, j = (n >> 6) & 63, i = n >> 12;
    const float inv63 = 1.0f/63.0f;
    float p0 = (float)(2*i - 63)*inv63;
    float p1 = (float)(2*j - 63)*inv63;
    float p2 = (float)(2*k - 63)*inv63;

    // new_loc = R @ p + t
    float nl0 = r0.x*p0 + r0.y*p1 + r0.z*p2 + r0.w;
    float nl1 = r1.x*p0 + r1.y*p1 + r1.z*p2 + r1.w;
    float nl2 = r2.x*p0 + r2.y*p1 + r2.z*p2 + r2.w;

    // samp = reversed(new_loc): x(W)<-nl2, y(H)<-nl1, z(D)<-nl0
    float gx = fminf(fmaxf((nl2 + 1.0f)*0.5f*63.0f, 0.0f), 63.0f);
    float gy = fminf(fmaxf((nl1 + 1.0f)*0.5f*63.0f, 0.0f), 63.0f);
    float gz = fminf(fmaxf((nl0 + 1.0f)*0.5f*63.0f, 0.0f), 63.0f);
    float x0f = floorf(gx), y0f = floorf(gy), z0f = floorf(gz);
    float fx = gx - x0f, fy = gy - y0f, fz = gz - z0f;
    int x0 = (int)x0f, y0 = (int)y0f, z0 = (int)z0f;
    int x1 = min(x0 + 1, 63), y1 = min(y0 + 1, 63), z1 = min(z0 + 1, 63);

    float w000 = (1.0f-fz)*(1.0f-fy)*(1.0f-fx);
    float w001 = (1.0f-fz)*(1.0f-fy)*fx;
    float w010 = (1.0f-fz)*fy*(1.0f-fx);
    float w011 = (1.0f-fz)*fy*fx;
    float w100 = fz*(1.0f-fy)*(1.0f-fx);
    float w101 = fz*(1.0f-fy)*fx;
    float w110 = fz*fy*(1.0f-fx);
    float w111 = fz*fy*fx;

    const float2* v2 = reinterpret_cast<const float2*>(vin);
    float acc0 = 0.f, acc1 = 0.f, acc2 = 0.f, acc3 = 0.f, acc4 = 0.f, acc5 = 0.f;
#define CORNER(zz_, yy_, xx_, ww_)                                              \
    {                                                                           \
        int b = ((((zz_) << 6) | (yy_)) << 6 | (xx_))*3;                        \
        float2 a = v2[b], bb = v2[b+1], cc = v2[b+2];                           \
        acc0 += (ww_)*a.x;  acc1 += (ww_)*a.y;                                  \
        acc2 += (ww_)*bb.x; acc3 += (ww_)*bb.y;                                 \
        acc4 += (ww_)*cc.x; acc5 += (ww_)*cc.y;                                 \
    }
    CORNER(z0, y0, x0, w000)
    CORNER(z0, y0, x1, w001)
    CORNER(z0, y1, x0, w010)
    CORNER(z0, y1, x1, w011)
    CORNER(z1, y0, x0, w100)
    CORNER(z1, y0, x1, w101)
    CORNER(z1, y1, x0, w110)
    CORNER(z1, y1, x1, w111)
#undef CORNER

    float interp[6] = {acc0, acc1, acc2, acc3, acc4, acc5};
    float R2[9], t2v[3];
    se3_exp_dev(interp, R2, t2v);

    // compose: mul_new = [R2|t2] * [Ro|to]
    float Rn[9], tn[3];
    Rn[0] = R2[0]*r0.x + R2[1]*r1.x + R2[2]*r2.x;
    Rn[1] = R2[0]*r0.y + R2[1]*r1.y + R2[2]*r2.y;
    Rn[2] = R2[0]*r0.z + R2[1]*r1.z + R2[2]*r2.z;
    Rn[3] = R2[3]*r0.x + R2[4]*r1.x + R2[5]*r2.x;
    Rn[4] = R2[3]*r0.y + R2[4]*r1.y + R2[5]*r2.y;
    Rn[5] = R2[3]*r0.z + R2[4]*r1.z + R2[5]*r2.z;
    Rn[6] = R2[6]*r0.x + R2[7]*r1.x + R2[8]*r2.x;
    Rn[7] = R2[6]*r0.y + R2[7]*r1.y + R2[8]*r2.y;
    Rn[8] = R2[6]*r0.z + R2[7]*r1.z + R2[8]*r2.z;
    tn[0] = R2[0]*r0.w + R2[1]*r1.w + R2[2]*r2.w + t2v[0];
    tn[1] = R2[3]*r0.w + R2[4]*r1.w + R2[5]*r2.w + t2v[1];
    tn[2] = R2[6]*r0.w + R2[7]*r1.w + R2[8]*r2.w + t2v[2];

    mp[0] = make_float4(Rn[0], Rn[1], Rn[2], tn[0]);
    mp[1] = make_float4(Rn[3], Rn[4], Rn[5], tn[1]);
    mp[2] = make_float4(Rn[6], Rn[7], Rn[8], tn[2]);

    float out6[6];
    se3_log_dev(Rn, tn, out6);
    float2* op = reinterpret_cast<float2*>(vout + (size_t)n*6);
    op[0] = make_float2(out6[0], out6[1]);
    op[1] = make_float2(out6[2], out6[3]);
    op[2] = make_float2(out6[4], out6[5]);
}

extern "C" void kernel_launch(void* const* d_in, const int* in_sizes, int n_in,
                              void* d_out, int out_size, void* d_ws, size_t ws_size,
                              hipStream_t stream) {
    (void)in_sizes; (void)n_in; (void)out_size; (void)ws_size;
    const float* in = (const float*)d_in[0];
    float* out = (float*)d_out;
    char*  ws  = (char*)d_ws;
    float* mul  = (float*)ws;                               // 12*NVOX floats = 12 MB
    float* vecA = (float*)(ws + (size_t)NVOX*12*sizeof(float)); // 6 MB

    dim3 blk(256), grid(NVOX/256);
    init_kernel<<<grid, blk, 0, stream>>>(in, vecA, mul);

    // v0 in vecA; odd steps write d_out, even steps write vecA; NSTEP=7 odd -> final in d_out
    const float* cur = vecA;
    for (int s = 1; s <= NSTEP; ++s) {
        float* dst = (s & 1) ? out : vecA;
        step_kernel<<<grid, blk, 0, stream>>>(cur, dst, mul);
        cur = dst;
    }
}

// Round 2
// 85.329 us; speedup vs baseline: 1.0333x; 1.0333x over previous
//
#include <hip/hip_runtime.h>
#include <math.h>

#define DSZ   64
#define NVOX  (DSZ*DSZ*DSZ)
#define NSTEP 7

__device__ __forceinline__ float rcp_f(float x)  { return __builtin_amdgcn_rcpf(x); }
__device__ __forceinline__ float rsq_f(float x)  { return __builtin_amdgcn_rsqf(x); }

// ---------- SE(3) exp: xi=(v,w) -> R(3x3 row-major), t(3) ----------
__device__ __forceinline__ void se3_exp_dev(const float xi[6], float R[9], float t[3]) {
    float vx = xi[0], vy = xi[1], vz = xi[2];
    float wx = xi[3], wy = xi[4], wz = xi[5];
    float t2 = wx*wx + wy*wy + wz*wz;
    float t2c = fmaxf(t2, 1e-20f);
    float it    = rsq_f(t2c);        // 1/theta
    float theta = t2c*it;            // theta
    float s = __sinf(theta), c = __cosf(theta);
    float it2 = it*it;
    float A = s*it;
    float B = (1.0f - c)*it2;
    float C = (theta - s)*it2*it;
    // small-angle: error in A/B/C is multiplied by theta^2 downstream -> 1e-3 is safe
    bool sm = t2 < 1e-6f;
    A = sm ? 1.0f - t2*(1.0f/6.0f)            : A;
    B = sm ? 0.5f - t2*(1.0f/24.0f)           : B;
    C = sm ? (1.0f/6.0f) - t2*(1.0f/120.0f)   : C;

    float xx = wx*wx, yy = wy*wy, zz = wz*wz;
    float xy = wx*wy, xz = wx*wz, yz = wy*wz;
    // R = I + A*Wm + B*W2
    R[0] = 1.0f - B*(yy+zz);
    R[1] = -A*wz + B*xy;
    R[2] =  A*wy + B*xz;
    R[3] =  A*wz + B*xy;
    R[4] = 1.0f - B*(xx+zz);
    R[5] = -A*wx + B*yz;
    R[6] = -A*wy + B*xz;
    R[7] =  A*wx + B*yz;
    R[8] = 1.0f - B*(xx+yy);
    // V = I + B*Wm + C*W2 ; t = V @ v
    float V0 = 1.0f - C*(yy+zz);
    float V1 = -B*wz + C*xy;
    float V2 =  B*wy + C*xz;
    float V3 =  B*wz + C*xy;
    float V4 = 1.0f - C*(xx+zz);
    float V5 = -B*wx + C*yz;
    float V6 = -B*wy + C*xz;
    float V7 =  B*wx + C*yz;
    float V8 = 1.0f - C*(xx+yy);
    t[0] = V0*vx + V1*vy + V2*vz;
    t[1] = V3*vx + V4*vy + V5*vz;
    t[2] = V6*vx + V7*vy + V8*vz;
}

// ---------- SE(3) log: R,t -> xi=(v,w) ----------
// Key: theta = acos(cs) => cos(theta)=cs, sin(theta)=sqrt(1-cs^2). No sincos needed.
__device__ __forceinline__ void se3_log_dev(const float R[9], const float t[3], float out[6]) {
    float tr = R[0] + R[4] + R[8];
    float cs = (tr - 1.0f)*0.5f;
    cs = fminf(fmaxf(cs, -1.0f + 1e-6f), 1.0f - 1e-6f);
    float theta = acosf(cs);
    float t2 = theta*theta;
    float ss2 = 1.0f - cs*cs;          // sin^2(theta) >= ~2e-6
    float isn = rsq_f(ss2);            // 1/sin
    float fac = theta*isn;             // theta/sin
    float sn  = ss2*isn;               // sin
    // coef = (1 - A/(2B))/t2, A/(2B) = sin*theta / (2*(1-cos))
    float coef = (1.0f - 0.5f*sn*theta*rcp_f(1.0f - cs)) * rcp_f(t2);
    bool sm = theta < 1e-3f;           // coef error scaled by theta^2 downstream
    fac  = sm ? 1.0f + t2*(1.0f/6.0f) : fac;
    coef = sm ? (1.0f/12.0f)          : coef;

    float wx = 0.5f*(R[7]-R[5])*fac;   // S[2][1]
    float wy = 0.5f*(R[2]-R[6])*fac;   // S[0][2]
    float wz = 0.5f*(R[3]-R[1])*fac;   // S[1][0]
    float xx = wx*wx, yy = wy*wy, zz = wz*wz;
    float xy = wx*wy, xz = wx*wz, yz = wy*wz;
    // Vinv = I - 0.5*Wm + coef*W2 ; v = Vinv @ t
    float V0 = 1.0f - coef*(yy+zz);
    float V1 =  0.5f*wz + coef*xy;
    float V2 = -0.5f*wy + coef*xz;
    float V3 = -0.5f*wz + coef*xy;
    float V4 = 1.0f - coef*(xx+zz);
    float V5 =  0.5f*wx + coef*yz;
    float V6 =  0.5f*wy + coef*xz;
    float V7 = -0.5f*wx + coef*yz;
    float V8 = 1.0f - coef*(xx+yy);
    out[0] = V0*t[0] + V1*t[1] + V2*t[2];
    out[1] = V3*t[0] + V4*t[1] + V5*t[2];
    out[2] = V6*t[0] + V7*t[1] + V8*t[2];
    out[3] = wx; out[4] = wy; out[5] = wz;
}

// ---------- init: transpose (6,N)->(N,6) * scale, and mulMat = exp ----------
__global__ __launch_bounds__(256) void init_kernel(const float* __restrict__ in,
                                                   float* __restrict__ vec,
                                                   float* __restrict__ mul) {
    int n = blockIdx.x*256 + threadIdx.x;
    const float scale = 1.0f/128.0f;  // 1/2^NSTEP
    float xi[6];
#pragma unroll
    for (int c = 0; c < 6; ++c) xi[c] = in[c*NVOX + n]*scale;
    float R[9], t[3];
    se3_exp_dev(xi, R, t);
    float4* mp = reinterpret_cast<float4*>(mul + (size_t)n*12);
    mp[0] = make_float4(R[0], R[1], R[2], t[0]);
    mp[1] = make_float4(R[3], R[4], R[5], t[1]);
    mp[2] = make_float4(R[6], R[7], R[8], t[2]);
    float2* vp = reinterpret_cast<float2*>(vec + (size_t)n*6);
    vp[0] = make_float2(xi[0], xi[1]);
    vp[1] = make_float2(xi[2], xi[3]);
    vp[2] = make_float2(xi[4], xi[5]);
}

// ---------- one squaring step ----------
__global__ __launch_bounds__(256) void step_kernel(const float* __restrict__ vin,
                                                   float* __restrict__ vout,
                                                   float* __restrict__ mul) {
    int n = blockIdx.x*256 + threadIdx.x;
    // load current mulMat (rows of [R|t])
    float4* mp = reinterpret_cast<float4*>(mul + (size_t)n*12);
    float4 r0 = mp[0], r1 = mp[1], r2 = mp[2];

    // fixed grid point for this voxel: n = i*4096 + j*64 + k, ax = (2*idx-63)/63
    int k = n & 63, j = (n >> 6) & 63, i = n >> 12;
    const float inv63 = 1.0f/63.0f;
    float p0 = (float)(2*i - 63)*inv63;
    float p1 = (float)(2*j - 63)*inv63;
    float p2 = (float)(2*k - 63)*inv63;

    // new_loc = R @ p + t
    float nl0 = r0.x*p0 + r0.y*p1 + r0.z*p2 + r0.w;
    float nl1 = r1.x*p0 + r1.y*p1 + r1.z*p2 + r1.w;
    float nl2 = r2.x*p0 + r2.y*p1 + r2.z*p2 + r2.w;

    // samp = reversed(new_loc): x(W)<-nl2, y(H)<-nl1, z(D)<-nl0
    float gx = fminf(fmaxf((nl2 + 1.0f)*0.5f*63.0f, 0.0f), 63.0f);
    float gy = fminf(fmaxf((nl1 + 1.0f)*0.5f*63.0f, 0.0f), 63.0f);
    float gz = fminf(fmaxf((nl0 + 1.0f)*0.5f*63.0f, 0.0f), 63.0f);
    float x0f = floorf(gx), y0f = floorf(gy), z0f = floorf(gz);
    float fx = gx - x0f, fy = gy - y0f, fz = gz - z0f;
    int x0 = (int)x0f, y0 = (int)y0f, z0 = (int)z0f;
    int x1 = min(x0 + 1, 63), y1 = min(y0 + 1, 63), z1 = min(z0 + 1, 63);

    float w000 = (1.0f-fz)*(1.0f-fy)*(1.0f-fx);
    float w001 = (1.0f-fz)*(1.0f-fy)*fx;
    float w010 = (1.0f-fz)*fy*(1.0f-fx);
    float w011 = (1.0f-fz)*fy*fx;
    float w100 = fz*(1.0f-fy)*(1.0f-fx);
    float w101 = fz*(1.0f-fy)*fx;
    float w110 = fz*fy*(1.0f-fx);
    float w111 = fz*fy*fx;

    const float2* v2 = reinterpret_cast<const float2*>(vin);
    float acc0 = 0.f, acc1 = 0.f, acc2 = 0.f, acc3 = 0.f, acc4 = 0.f, acc5 = 0.f;
#define CORNER(zz_, yy_, xx_, ww_)                                              \
    {                                                                           \
        int b = ((((zz_) << 6) | (yy_)) << 6 | (xx_))*3;                        \
        float2 a = v2[b], bb = v2[b+1], cc = v2[b+2];                           \
        acc0 += (ww_)*a.x;  acc1 += (ww_)*a.y;                                  \
        acc2 += (ww_)*bb.x; acc3 += (ww_)*bb.y;                                 \
        acc4 += (ww_)*cc.x; acc5 += (ww_)*cc.y;                                 \
    }
    CORNER(z0, y0, x0, w000)
    CORNER(z0, y0, x1, w001)
    CORNER(z0, y1, x0, w010)
    CORNER(z0, y1, x1, w011)
    CORNER(z1, y0, x0, w100)
    CORNER(z1, y0, x1, w101)
    CORNER(z1, y1, x0, w110)
    CORNER(z1, y1, x1, w111)
#undef CORNER

    float interp[6] = {acc0, acc1, acc2, acc3, acc4, acc5};
    float R2[9], t2v[3];
    se3_exp_dev(interp, R2, t2v);

    // compose: mul_new = [R2|t2] * [Ro|to]
    float Rn[9], tn[3];
    Rn[0] = R2[0]*r0.x + R2[1]*r1.x + R2[2]*r2.x;
    Rn[1] = R2[0]*r0.y + R2[1]*r1.y + R2[2]*r2.y;
    Rn[2] = R2[0]*r0.z + R2[1]*r1.z + R2[2]*r2.z;
    Rn[3] = R2[3]*r0.x + R2[4]*r1.x + R2[5]*r2.x;
    Rn[4] = R2[3]*r0.y + R2[4]*r1.y + R2[5]*r2.y;
    Rn[5] = R2[3]*r0.z + R2[4]*r1.z + R2[5]*r2.z;
    Rn[6] = R2[6]*r0.x + R2[7]*r1.x + R2[8]*r2.x;
    Rn[7] = R2[6]*r0.y + R2[7]*r1.y + R2[8]*r2.y;
    Rn[8] = R2[6]*r0.z + R2[7]*r1.z + R2[8]*r2.z;
    tn[0] = R2[0]*r0.w + R2[1]*r1.w + R2[2]*r2.w + t2v[0];
    tn[1] = R2[3]*r0.w + R2[4]*r1.w + R2[5]*r2.w + t2v[1];
    tn[2] = R2[6]*r0.w + R2[7]*r1.w + R2[8]*r2.w + t2v[2];

    mp[0] = make_float4(Rn[0], Rn[1], Rn[2], tn[0]);
    mp[1] = make_float4(Rn[3], Rn[4], Rn[5], tn[1]);
    mp[2] = make_float4(Rn[6], Rn[7], Rn[8], tn[2]);

    float out6[6];
    se3_log_dev(Rn, tn, out6);
    float2* op = reinterpret_cast<float2*>(vout + (size_t)n*6);
    op[0] = make_float2(out6[0], out6[1]);
    op[1] = make_float2(out6[2], out6[3]);
    op[2] = make_float2(out6[4], out6[5]);
}

extern "C" void kernel_launch(void* const* d_in, const int* in_sizes, int n_in,
                              void* d_out, int out_size, void* d_ws, size_t ws_size,
                              hipStream_t stream) {
    (void)in_sizes; (void)n_in; (void)out_size; (void)ws_size;
    const float* in = (const float*)d_in[0];
    float* out = (float*)d_out;
    char*  ws  = (char*)d_ws;
    float* mul  = (float*)ws;                                   // 12*NVOX floats = 12 MB
    float* vecA = (float*)(ws + (size_t)NVOX*12*sizeof(float)); // 6 MB

    dim3 blk(256), grid(NVOX/256);
    init_kernel<<<grid, blk, 0, stream>>>(in, vecA, mul);

    // v0 in vecA; odd steps write d_out, even steps write vecA; NSTEP=7 odd -> final in d_out
    const float* cur = vecA;
    for (int s = 1; s <= NSTEP; ++s) {
        float* dst = (s & 1) ? out : vecA;
        step_kernel<<<grid, blk, 0, stream>>>(cur, dst, mul);
        cur = dst;
    }
}

// Round 4
// 72.782 us; speedup vs baseline: 1.2114x; 1.1724x over previous
//
#include <hip/hip_runtime.h>
#include <math.h>

#define DSZ   64
#define NVOX  (DSZ*DSZ*DSZ)
#define NSTEP 7

__device__ __forceinline__ float rcp_f(float x)  { return __builtin_amdgcn_rcpf(x); }
__device__ __forceinline__ float rsq_f(float x)  { return __builtin_amdgcn_rsqf(x); }

// ---------- SE(3) exp: xi=(v,w) -> R(3x3 row-major), t(3) ----------
__device__ __forceinline__ void se3_exp_dev(const float xi[6], float R[9], float t[3]) {
    float vx = xi[0], vy = xi[1], vz = xi[2];
    float wx = xi[3], wy = xi[4], wz = xi[5];
    float t2 = wx*wx + wy*wy + wz*wz;
    float t2c = fmaxf(t2, 1e-20f);
    float it    = rsq_f(t2c);        // 1/theta
    float theta = t2c*it;            // theta
    float s = __sinf(theta), c = __cosf(theta);
    float it2 = it*it;
    float A = s*it;
    float B = (1.0f - c)*it2;
    float C = (theta - s)*it2*it;
    bool sm = t2 < 1e-6f;            // error in A/B/C is *theta^2 downstream
    A = sm ? 1.0f - t2*(1.0f/6.0f)            : A;
    B = sm ? 0.5f - t2*(1.0f/24.0f)           : B;
    C = sm ? (1.0f/6.0f) - t2*(1.0f/120.0f)   : C;

    float xx = wx*wx, yy = wy*wy, zz = wz*wz;
    float xy = wx*wy, xz = wx*wz, yz = wy*wz;
    R[0] = 1.0f - B*(yy+zz);
    R[1] = -A*wz + B*xy;
    R[2] =  A*wy + B*xz;
    R[3] =  A*wz + B*xy;
    R[4] = 1.0f - B*(xx+zz);
    R[5] = -A*wx + B*yz;
    R[6] = -A*wy + B*xz;
    R[7] =  A*wx + B*yz;
    R[8] = 1.0f - B*(xx+yy);
    float V0 = 1.0f - C*(yy+zz);
    float V1 = -B*wz + C*xy;
    float V2 =  B*wy + C*xz;
    float V3 =  B*wz + C*xy;
    float V4 = 1.0f - C*(xx+zz);
    float V5 = -B*wx + C*yz;
    float V6 = -B*wy + C*xz;
    float V7 =  B*wx + C*yz;
    float V8 = 1.0f - C*(xx+yy);
    t[0] = V0*vx + V1*vy + V2*vz;
    t[1] = V3*vx + V4*vy + V5*vz;
    t[2] = V6*vx + V7*vy + V8*vz;
}

// ---------- SE(3) log: R,t -> xi=(v,w); sin recovered from cos ----------
__device__ __forceinline__ void se3_log_dev(const float R[9], const float t[3], float out[6]) {
    float tr = R[0] + R[4] + R[8];
    float cs = (tr - 1.0f)*0.5f;
    cs = fminf(fmaxf(cs, -1.0f + 1e-6f), 1.0f - 1e-6f);
    float theta = acosf(cs);
    float t2 = theta*theta;
    float ss2 = 1.0f - cs*cs;          // sin^2
    float isn = rsq_f(ss2);            // 1/sin
    float fac = theta*isn;             // theta/sin
    float sn  = ss2*isn;               // sin
    float coef = (1.0f - 0.5f*sn*theta*rcp_f(1.0f - cs)) * rcp_f(t2);
    bool sm = theta < 1e-3f;
    fac  = sm ? 1.0f + t2*(1.0f/6.0f) : fac;
    coef = sm ? (1.0f/12.0f)          : coef;

    float wx = 0.5f*(R[7]-R[5])*fac;
    float wy = 0.5f*(R[2]-R[6])*fac;
    float wz = 0.5f*(R[3]-R[1])*fac;
    float xx = wx*wx, yy = wy*wy, zz = wz*wz;
    float xy = wx*wy, xz = wx*wz, yz = wy*wz;
    float V0 = 1.0f - coef*(yy+zz);
    float V1 =  0.5f*wz + coef*xy;
    float V2 = -0.5f*wy + coef*xz;
    float V3 = -0.5f*wz + coef*xy;
    float V4 = 1.0f - coef*(xx+zz);
    float V5 =  0.5f*wx + coef*yz;
    float V6 =  0.5f*wy + coef*xz;
    float V7 = -0.5f*wx + coef*yz;
    float V8 = 1.0f - coef*(xx+yy);
    out[0] = V0*t[0] + V1*t[1] + V2*t[2];
    out[1] = V3*t[0] + V4*t[1] + V5*t[2];
    out[2] = V6*t[0] + V7*t[1] + V8*t[2];
    out[3] = wx; out[4] = wy; out[5] = wz;
}

// ---------- init: pure transpose (6,N)->(N,6) * scale ----------
__global__ __launch_bounds__(256) void init_kernel(const float* __restrict__ in,
                                                   float* __restrict__ vec) {
    int n = blockIdx.x*256 + threadIdx.x;
    const float scale = 1.0f/128.0f;  // 1/2^NSTEP
    float xi[6];
#pragma unroll
    for (int c = 0; c < 6; ++c) xi[c] = in[c*NVOX + n]*scale;
    float2* vp = reinterpret_cast<float2*>(vec + (size_t)n*6);
    vp[0] = make_float2(xi[0], xi[1]);
    vp[1] = make_float2(xi[2], xi[3]);
    vp[2] = make_float2(xi[4], xi[5]);
}

// ---------- one squaring step: mulMat recomputed as exp(own vec_f) ----------
__global__ __launch_bounds__(256) void step_kernel(const float* __restrict__ vin,
                                                   float* __restrict__ vout) {
    int n = blockIdx.x*256 + threadIdx.x;

    // rebuild mulMat from this voxel's own field value (exp o log == id)
    const float2* v2 = reinterpret_cast<const float2*>(vin);
    float2 o0 = v2[n*3], o1 = v2[n*3+1], o2 = v2[n*3+2];
    float xi_own[6] = {o0.x, o0.y, o1.x, o1.y, o2.x, o2.y};
    float Rm[9], tm[3];
    se3_exp_dev(xi_own, Rm, tm);

    // fixed grid point: n = i*4096 + j*64 + k, ax = (2*idx-63)/63
    int k = n & 63, j = (n >> 6) & 63, i = n >> 12;
    const float inv63 = 1.0f/63.0f;
    float p0 = (float)(2*i - 63)*inv63;
    float p1 = (float)(2*j - 63)*inv63;
    float p2 = (float)(2*k - 63)*inv63;

    // new_loc = R @ p + t
    float nl0 = Rm[0]*p0 + Rm[1]*p1 + Rm[2]*p2 + tm[0];
    float nl1 = Rm[3]*p0 + Rm[4]*p1 + Rm[5]*p2 + tm[1];
    float nl2 = Rm[6]*p0 + Rm[7]*p1 + Rm[8]*p2 + tm[2];

    // samp reversed: x<-nl2, y<-nl1, z<-nl0
    float gx = fminf(fmaxf((nl2 + 1.0f)*0.5f*63.0f, 0.0f), 63.0f);
    float gy = fminf(fmaxf((nl1 + 1.0f)*0.5f*63.0f, 0.0f), 63.0f);
    float gz = fminf(fmaxf((nl0 + 1.0f)*0.5f*63.0f, 0.0f), 63.0f);
    float x0f = floorf(gx), y0f = floorf(gy), z0f = floorf(gz);
    float fx = gx - x0f, fy = gy - y0f, fz = gz - z0f;
    int x0 = (int)x0f, y0 = (int)y0f, z0 = (int)z0f;
    int x1 = min(x0 + 1, 63), y1 = min(y0 + 1, 63), z1 = min(z0 + 1, 63);

    float w000 = (1.0f-fz)*(1.0f-fy)*(1.0f-fx);
    float w001 = (1.0f-fz)*(1.0f-fy)*fx;
    float w010 = (1.0f-fz)*fy*(1.0f-fx);
    float w011 = (1.0f-fz)*fy*fx;
    float w100 = fz*(1.0f-fy)*(1.0f-fx);
    float w101 = fz*(1.0f-fy)*fx;
    float w110 = fz*fy*(1.0f-fx);
    float w111 = fz*fy*fx;

    float acc0 = 0.f, acc1 = 0.f, acc2 = 0.f, acc3 = 0.f, acc4 = 0.f, acc5 = 0.f;
#define CORNER(zz_, yy_, xx_, ww_)                                              \
    {                                                                           \
        int b = ((((zz_) << 6) | (yy_)) << 6 | (xx_))*3;                        \
        float2 a = v2[b], bb = v2[b+1], cc = v2[b+2];                           \
        acc0 += (ww_)*a.x;  acc1 += (ww_)*a.y;                                  \
        acc2 += (ww_)*bb.x; acc3 += (ww_)*bb.y;                                 \
        acc4 += (ww_)*cc.x; acc5 += (ww_)*cc.y;                                 \
    }
    CORNER(z0, y0, x0, w000)
    CORNER(z0, y0, x1, w001)
    CORNER(z0, y1, x0, w010)
    CORNER(z0, y1, x1, w011)
    CORNER(z1, y0, x0, w100)
    CORNER(z1, y0, x1, w101)
    CORNER(z1, y1, x0, w110)
    CORNER(z1, y1, x1, w111)
#undef CORNER

    float interp[6] = {acc0, acc1, acc2, acc3, acc4, acc5};
    float R2[9], t2v[3];
    se3_exp_dev(interp, R2, t2v);

    // compose: Mn = [R2|t2] * [Rm|tm]
    float Rn[9], tn[3];
    Rn[0] = R2[0]*Rm[0] + R2[1]*Rm[3] + R2[2]*Rm[6];
    Rn[1] = R2[0]*Rm[1] + R2[1]*Rm[4] + R2[2]*Rm[7];
    Rn[2] = R2[0]*Rm[2] + R2[1]*Rm[5] + R2[2]*Rm[8];
    Rn[3] = R2[3]*Rm[0] + R2[4]*Rm[3] + R2[5]*Rm[6];
    Rn[4] = R2[3]*Rm[1] + R2[4]*Rm[4] + R2[5]*Rm[7];
    Rn[5] = R2[3]*Rm[2] + R2[4]*Rm[5] + R2[5]*Rm[8];
    Rn[6] = R2[6]*Rm[0] + R2[7]*Rm[3] + R2[8]*Rm[6];
    Rn[7] = R2[6]*Rm[1] + R2[7]*Rm[4] + R2[8]*Rm[7];
    Rn[8] = R2[6]*Rm[2] + R2[7]*Rm[5] + R2[8]*Rm[8];
    tn[0] = R2[0]*tm[0] + R2[1]*tm[1] + R2[2]*tm[2] + t2v[0];
    tn[1] = R2[3]*tm[0] + R2[4]*tm[1] + R2[5]*tm[2] + t2v[1];
    tn[2] = R2[6]*tm[0] + R2[7]*tm[1] + R2[8]*tm[2] + t2v[2];

    float out6[6];
    se3_log_dev(Rn, tn, out6);
    float2* op = reinterpret_cast<float2*>(vout + (size_t)n*6);
    op[0] = make_float2(out6[0], out6[1]);
    op[1] = make_float2(out6[2], out6[3]);
    op[2] = make_float2(out6[4], out6[5]);
}

extern "C" void kernel_launch(void* const* d_in, const int* in_sizes, int n_in,
                              void* d_out, int out_size, void* d_ws, size_t ws_size,
                              hipStream_t stream) {
    (void)in_sizes; (void)n_in; (void)out_size; (void)ws_size;
    const float* in = (const float*)d_in[0];
    float* out  = (float*)d_out;
    float* vecA = (float*)d_ws;   // 6 MB ping buffer

    dim3 blk(256), grid(NVOX/256);
    init_kernel<<<grid, blk, 0, stream>>>(in, vecA);

    // v0 in vecA; odd steps write d_out, even steps write vecA; NSTEP=7 odd -> final in d_out
    const float* cur = vecA;
    for (int s = 1; s <= NSTEP; ++s) {
        float* dst = (s & 1) ? out : vecA;
        step_kernel<<<grid, blk, 0, stream>>>(cur, dst);
        cur = dst;
    }
}